// Round 12
// baseline (123.779 us; speedup 1.0000x reference)
//
#include <hip/hip_runtime.h>
#include <math.h>

// DTW loss: B=128, L1=L2=512, D=16.
// R12: 4-wave column-split skewed systolic (R11 logic) with REGISTER x-flow:
//  - the x row travels lane->lane via 17 wave_shr:1 DPPs per substep
//    (16 floats + sq); fresh row enters at lane 0 through the DPP `old`
//    operand (lane 0's wave_shr source is invalid -> takes old = fresh)
//  - only wave-uniform BROADCAST LDS reads remain (fresh row ring of 4,
//    static indexing, counted s_waitcnt lgkmcnt(10) + sched_barrier)
//  - everything else (packets, carry, freeze, barriers) identical to R11

#define TL 512
#define TD 16
#define TNB 128
#define BIGF 3.0e38f
#define INFF __builtin_inff()
#define XSTR 20    // floats per padded LDS row (80 B; sq at +64 B)
#define WOFF 71
#define EP 8
#define NE 99

typedef float f32x2 __attribute__((ext_vector_type(2)));
typedef float f32x4 __attribute__((ext_vector_type(4)));

__device__ inline f32x2 pk_fma(f32x2 a, f32x2 b, f32x2 c) {
    f32x2 d;
    asm("v_pk_fma_f32 %0, %1, %2, %3" : "=v"(d) : "v"(a), "v"(b), "v"(c));
    return d;
}
__device__ inline f32x2 pk_mul(f32x2 a, f32x2 b) {
    f32x2 d;
    asm("v_pk_mul_f32 %0, %1, %2" : "=v"(d) : "v"(a), "v"(b));
    return d;
}
__device__ inline float min3f(float a, float b, float c) {
    float d;
    asm("v_min3_f32 %0, %1, %2, %3" : "=v"(d) : "v"(a), "v"(b), "v"(c));
    return d;
}
// wave_shr:1; invalid lane 0 takes `old`
__device__ inline float dsh(float old_, float src) {
    return __int_as_float(__builtin_amdgcn_update_dpp(
        __float_as_int(old_), __float_as_int(src), 0x138, 0xf, 0xf, false));
}

struct XF { f32x4 q0, q1, q2, q3; float sq; };   // fresh-row buffer (17 regs)

// issue 5 broadcast DS reads (wave-uniform address) for clamped row r
__device__ inline void fissue(unsigned base, int r, XF& x) {
    int rc = r < 0 ? 0 : (r > TL - 1 ? TL - 1 : r);
    unsigned a = base + (unsigned)(rc * (XSTR * 4));
    asm volatile("ds_read_b128 %0, %1 offset:0"  : "=v"(x.q0) : "v"(a));
    asm volatile("ds_read_b128 %0, %1 offset:16" : "=v"(x.q1) : "v"(a));
    asm volatile("ds_read_b128 %0, %1 offset:32" : "=v"(x.q2) : "v"(a));
    asm volatile("ds_read_b128 %0, %1 offset:48" : "=v"(x.q3) : "v"(a));
    asm volatile("ds_read_b32  %0, %1 offset:64" : "=v"(x.sq) : "v"(a));
}

#define WAITC() { asm volatile("s_waitcnt lgkmcnt(10)" ::: "memory"); \
                  __builtin_amdgcn_sched_barrier(0); }

// shift the x-flow down one lane; lane 0 receives the fresh row f
__device__ inline void xshift(const XF& f, f32x2 (&X)[8], float& Xsq) {
    X[0].x = dsh(f.q0.x, X[0].x); X[0].y = dsh(f.q0.y, X[0].y);
    X[1].x = dsh(f.q0.z, X[1].x); X[1].y = dsh(f.q0.w, X[1].y);
    X[2].x = dsh(f.q1.x, X[2].x); X[2].y = dsh(f.q1.y, X[2].y);
    X[3].x = dsh(f.q1.z, X[3].x); X[3].y = dsh(f.q1.w, X[3].y);
    X[4].x = dsh(f.q2.x, X[4].x); X[4].y = dsh(f.q2.y, X[4].y);
    X[5].x = dsh(f.q2.z, X[5].x); X[5].y = dsh(f.q2.w, X[5].y);
    X[6].x = dsh(f.q3.x, X[6].x); X[6].y = dsh(f.q3.y, X[6].y);
    X[7].x = dsh(f.q3.z, X[7].x); X[7].y = dsh(f.q3.w, X[7].y);
    Xsq    = dsh(f.sq,   Xsq);
}

__device__ inline void sub(const f32x2 (&X)[8], float Xsq, int r,
                           const f32x2 (&y0)[8], const f32x2 (&y1)[8],
                           f32x2 ys0, f32x2 ys1,
                           float& pv0, float& pv1, float& o1,
                           float bL, float bD, bool lane0) {
    f32x2 a0 = ys0, a1 = ys1;                    // {ysq, 0}; y pre-scaled -2
    #pragma unroll
    for (int k = 0; k < 8; ++k) {
        a0 = pk_fma(X[k], y0[k], a0);
        a1 = pk_fma(X[k], y1[k], a1);
    }
    const float c0 = Xsq + (a0.x + a0.y);
    const float c1 = Xsq + (a1.x + a1.y);

    float left = dsh(BIGF, pv1);   // lane-1: DTW[r][j0-1]
    float diag = dsh(BIGF, o1);    // lane-1: DTW[r-1][j0-1]
    if (lane0) { left = bL; diag = bD; }
    o1 = pv1;

    const float v0 = c0 + min3f(pv0, left, diag);
    const float v1 = c1 + min3f(pv1, v0, pv0);
    const bool valid = (unsigned)r < (unsigned)TL;
    pv0 = valid ? v0 : pv0;
    pv1 = valid ? v1 : pv1;
}

__global__ __launch_bounds__(256, 1) void dtw_split_kernel(const float* __restrict__ s1,
                                                           const float* __restrict__ s2,
                                                           float* __restrict__ ws) {
    const int b   = blockIdx.x;
    const int tid = threadIdx.x;
    const int W   = tid >> 6;    // wave 0..3
    const int l   = tid & 63;

    __shared__ float xlds[TL * XSTR];   // 40,960 B (16 x-floats + sq per row)
    __shared__ f32x4 pkt[2][4][2];      // boundary packets (8 rows each)

    const float* s1b = s1 + (size_t)b * TL * TD;

    // stage s1 rows (2/thread) + row sumsq
    #pragma unroll
    for (int q = 0; q < 2; ++q) {
        const int r = 2 * tid + q;
        const f32x4* src = (const f32x4*)(s1b + r * TD);
        f32x4 q0 = src[0], q1 = src[1], q2 = src[2], q3 = src[3];
        f32x4* dst = (f32x4*)(xlds + r * XSTR);
        dst[0] = q0; dst[1] = q1; dst[2] = q2; dst[3] = q3;
        f32x2 a_ = pk_mul(f32x2{q0.x, q0.y}, f32x2{q0.x, q0.y});
        a_ = pk_fma(f32x2{q0.z, q0.w}, f32x2{q0.z, q0.w}, a_);
        a_ = pk_fma(f32x2{q1.x, q1.y}, f32x2{q1.x, q1.y}, a_);
        a_ = pk_fma(f32x2{q1.z, q1.w}, f32x2{q1.z, q1.w}, a_);
        a_ = pk_fma(f32x2{q2.x, q2.y}, f32x2{q2.x, q2.y}, a_);
        a_ = pk_fma(f32x2{q2.z, q2.w}, f32x2{q2.z, q2.w}, a_);
        a_ = pk_fma(f32x2{q3.x, q3.y}, f32x2{q3.x, q3.y}, a_);
        a_ = pk_fma(f32x2{q3.z, q3.w}, f32x2{q3.z, q3.w}, a_);
        xlds[r * XSTR + 16] = a_.x + a_.y;
    }
    if (tid < 64) ((float*)pkt)[tid] = BIGF;

    // y tile: 2 cols/lane; prescale -2; acc seeds {ysq, 0}
    const int j0 = 2 * (64 * W + l);
    f32x2 y0[8], y1[8];
    const float* yp0 = s2 + ((size_t)b * TL + j0) * TD;
    #pragma unroll
    for (int k = 0; k < 8; ++k) {
        y0[k] = *(const f32x2*)(yp0 + 2 * k);
        y1[k] = *(const f32x2*)(yp0 + TD + 2 * k);
    }
    f32x2 s0a = pk_mul(y0[0], y0[0]), s1a = pk_mul(y1[0], y1[0]);
    #pragma unroll
    for (int k = 1; k < 8; ++k) {
        s0a = pk_fma(y0[k], y0[k], s0a);
        s1a = pk_fma(y1[k], y1[k], s1a);
    }
    const f32x2 ys0 = {s0a.x + s0a.y, 0.f};
    const f32x2 ys1 = {s1a.x + s1a.y, 0.f};
    #pragma unroll
    for (int k = 0; k < 8; ++k) {
        y0[k] = pk_mul(y0[k], f32x2{-2.f, -2.f});
        y1[k] = pk_mul(y1[k], f32x2{-2.f, -2.f});
    }

    __syncthreads();

    const unsigned base = (unsigned)(uintptr_t)&xlds[0];
    const int gL = WOFF * W + l;
    const int rw = -WOFF * W;            // lane0's row offset
    const bool lane0 = (l == 0);
    float pv0 = INFF, pv1 = INFF, o1 = INFF;
    float carry = (W == 0) ? 0.f : BIGF;

    f32x2 X[8] = {};                     // x-flow state (garbage until valid;
    float Xsq = 0.f;                     //  zero-init avoids NaN surprises)

    XF f0, f1, f2, f3;                   // fresh ring (static indexing)
    fissue(base, rw + 0, f0);
    fissue(base, rw + 1, f1);
    fissue(base, rw + 2, f2);

    for (int e = 0; e < NE; ++e) {
        float lb0 = BIGF, lb1 = BIGF, lb2 = BIGF, lb3 = BIGF;
        float lb4 = BIGF, lb5 = BIGF, lb6 = BIGF, lb7 = BIGF;
        if (W > 0) {
            f32x4 pA = pkt[(e + 1) & 1][W - 1][0];
            f32x4 pB = pkt[(e + 1) & 1][W - 1][1];
            lb0 = pA.x; lb1 = pA.y; lb2 = pA.z; lb3 = pA.w;
            lb4 = pB.x; lb5 = pB.y; lb6 = pB.z; lb7 = pB.w;
        }
        const int rb  = EP * e - gL;     // lane's row base this epoch
        const int rl0 = EP * e + rw;     // lane0's row base this epoch
        float t0, t1, t2, t3, t4, t5, t6, t7;

        WAITC(); xshift(f0, X, Xsq); fissue(base, rl0 + 3,  f3);
        sub(X, Xsq, rb + 0, y0, y1, ys0, ys1, pv0, pv1, o1, lb0, carry, lane0); t0 = pv1;
        WAITC(); xshift(f1, X, Xsq); fissue(base, rl0 + 4,  f0);
        sub(X, Xsq, rb + 1, y0, y1, ys0, ys1, pv0, pv1, o1, lb1, lb0, lane0);   t1 = pv1;
        WAITC(); xshift(f2, X, Xsq); fissue(base, rl0 + 5,  f1);
        sub(X, Xsq, rb + 2, y0, y1, ys0, ys1, pv0, pv1, o1, lb2, lb1, lane0);   t2 = pv1;
        WAITC(); xshift(f3, X, Xsq); fissue(base, rl0 + 6,  f2);
        sub(X, Xsq, rb + 3, y0, y1, ys0, ys1, pv0, pv1, o1, lb3, lb2, lane0);   t3 = pv1;
        WAITC(); xshift(f0, X, Xsq); fissue(base, rl0 + 7,  f3);
        sub(X, Xsq, rb + 4, y0, y1, ys0, ys1, pv0, pv1, o1, lb4, lb3, lane0);   t4 = pv1;
        WAITC(); xshift(f1, X, Xsq); fissue(base, rl0 + 8,  f0);
        sub(X, Xsq, rb + 5, y0, y1, ys0, ys1, pv0, pv1, o1, lb5, lb4, lane0);   t5 = pv1;
        WAITC(); xshift(f2, X, Xsq); fissue(base, rl0 + 9,  f1);
        sub(X, Xsq, rb + 6, y0, y1, ys0, ys1, pv0, pv1, o1, lb6, lb5, lane0);   t6 = pv1;
        WAITC(); xshift(f3, X, Xsq); fissue(base, rl0 + 10, f2);
        sub(X, Xsq, rb + 7, y0, y1, ys0, ys1, pv0, pv1, o1, lb7, lb6, lane0);   t7 = pv1;

        carry = lb7;

        if (l == 63 && W < 3) {
            pkt[e & 1][W][0] = f32x4{t0, t1, t2, t3};
            pkt[e & 1][W][1] = f32x4{t4, t5, t6, t7};
        }
        __syncthreads();
    }

    if (W == 3 && l == 63) ws[b] = sqrtf(pv1);   // DTW[511][511]
}

__global__ void dtw_reduce_kernel(const float* __restrict__ ws, float* __restrict__ out) {
    const int t = threadIdx.x;          // 64 threads
    float v = ws[t] + ws[t + 64];
    #pragma unroll
    for (int d2 = 32; d2 > 0; d2 >>= 1) v += __shfl_down(v, d2);
    if (t == 0) out[0] = v * (1.0f / TNB);
}

extern "C" void kernel_launch(void* const* d_in, const int* in_sizes, int n_in,
                              void* d_out, int out_size, void* d_ws, size_t ws_size,
                              hipStream_t stream) {
    const float* s1 = (const float*)d_in[0];
    const float* s2 = (const float*)d_in[1];
    float* ws  = (float*)d_ws;
    float* out = (float*)d_out;

    dtw_split_kernel<<<TNB, 256, 0, stream>>>(s1, s2, ws);
    dtw_reduce_kernel<<<1, 64, 0, stream>>>(ws, out);
}

// Round 13
// 95.952 us; speedup vs baseline: 1.2900x; 1.2900x over previous
//
#include <hip/hip_runtime.h>
#include <math.h>

// DTW loss: B=128, L1=L2=512, D=16.
// R13 = R11 (4-wave column-split skewed systolic, asm-pinned ring-4 pipeline)
// with a CONFLICT-FREE x layout: column-major-by-quad planes.
//   xT[q][r] (f32x4, plane stride 8 KB) : row r's 16B quad q
//   sqT[r]                              : row r's sum-of-squares
// At a substep lane l reads row R-l -> consecutive lanes hit consecutive 16B
// addresses in each plane: each 8-lane b128 phase = one full 128B bank sweep,
// zero conflicts (vs R11's structural 8-way on row-major strides).
// DP cells, packets, carry, freeze, barriers: identical to R11 (verified).

#define TL 512
#define TD 16
#define TNB 128
#define BIGF 3.0e38f
#define INFF __builtin_inff()
#define WOFF 71
#define EP 8
#define NE 99

typedef float f32x2 __attribute__((ext_vector_type(2)));
typedef float f32x4 __attribute__((ext_vector_type(4)));

__device__ inline f32x2 pk_fma(f32x2 a, f32x2 b, f32x2 c) {
    f32x2 d;
    asm("v_pk_fma_f32 %0, %1, %2, %3" : "=v"(d) : "v"(a), "v"(b), "v"(c));
    return d;
}
__device__ inline f32x2 pk_mul(f32x2 a, f32x2 b) {
    f32x2 d;
    asm("v_pk_mul_f32 %0, %1, %2" : "=v"(d) : "v"(a), "v"(b));
    return d;
}
__device__ inline float min3f(float a, float b, float c) {
    float d;
    asm("v_min3_f32 %0, %1, %2, %3" : "=v"(d) : "v"(a), "v"(b), "v"(c));
    return d;
}
template<int CTRL, int RM, bool BC>
__device__ inline float dpp_mov(float old_, float src) {
    return __int_as_float(__builtin_amdgcn_update_dpp(
        __float_as_int(old_), __float_as_int(src), CTRL, RM, 0xf, BC));
}

struct XR { f32x4 q0, q1, q2, q3; float sq; };

// issue 5 DS reads for clamped row r from the quad planes (conflict-free)
__device__ inline void xissue(unsigned xb, unsigned sb, int r, XR& x) {
    int rc = r < 0 ? 0 : (r > TL - 1 ? TL - 1 : r);
    unsigned a16 = xb + ((unsigned)rc << 4);
    unsigned a4  = sb + ((unsigned)rc << 2);
    asm volatile("ds_read_b128 %0, %1 offset:0"     : "=v"(x.q0) : "v"(a16));
    asm volatile("ds_read_b128 %0, %1 offset:8192"  : "=v"(x.q1) : "v"(a16));
    asm volatile("ds_read_b128 %0, %1 offset:16384" : "=v"(x.q2) : "v"(a16));
    asm volatile("ds_read_b128 %0, %1 offset:24576" : "=v"(x.q3) : "v"(a16));
    asm volatile("ds_read_b32  %0, %1 offset:0"     : "=v"(x.sq) : "v"(a4));
}

// wait until <=10 DS ops outstanding: drains exactly the substep's buffer
#define WAITC() { asm volatile("s_waitcnt lgkmcnt(10)" ::: "memory"); \
                  __builtin_amdgcn_sched_barrier(0); }

__device__ inline void sub(const XR& x, int r,
                           const f32x2 (&y0)[8], const f32x2 (&y1)[8],
                           f32x2 ys0, f32x2 ys1,
                           float& pv0, float& pv1, float& o1,
                           float bL, float bD, bool lane0) {
    const f32x2* xd = (const f32x2*)&x;          // q0..q3 as 8 f32x2
    f32x2 a0 = ys0, a1 = ys1;                    // {ysq, 0}; y pre-scaled -2
    #pragma unroll
    for (int k = 0; k < 8; ++k) {
        a0 = pk_fma(xd[k], y0[k], a0);
        a1 = pk_fma(xd[k], y1[k], a1);
    }
    const float c0 = x.sq + (a0.x + a0.y);
    const float c1 = x.sq + (a1.x + a1.y);

    float left = dpp_mov<0x138, 0xf, false>(BIGF, pv1);  // DTW[r][j0-1]
    float diag = dpp_mov<0x138, 0xf, false>(BIGF, o1);   // DTW[r-1][j0-1]
    if (lane0) { left = bL; diag = bD; }
    o1 = pv1;

    const float v0 = c0 + min3f(pv0, left, diag);
    const float v1 = c1 + min3f(pv1, v0, pv0);
    const bool valid = (unsigned)r < (unsigned)TL;
    pv0 = valid ? v0 : pv0;
    pv1 = valid ? v1 : pv1;
}

__global__ __launch_bounds__(256, 1) void dtw_split_kernel(const float* __restrict__ s1,
                                                           const float* __restrict__ s2,
                                                           float* __restrict__ ws) {
    const int b   = blockIdx.x;
    const int tid = threadIdx.x;
    const int W   = tid >> 6;    // wave 0..3
    const int l   = tid & 63;

    __shared__ f32x4 xT[4][TL];         // 32 KB quad planes (stride 8 KB)
    __shared__ float sqT[TL];           // 2 KB row sumsq
    __shared__ f32x4 pkt[2][4][2];      // boundary packets (8 rows each)

    const float* s1b = s1 + (size_t)b * TL * TD;

    // stage s1 rows (2/thread) into quad planes + sumsq
    #pragma unroll
    for (int q = 0; q < 2; ++q) {
        const int r = 2 * tid + q;
        const f32x4* src = (const f32x4*)(s1b + r * TD);
        f32x4 q0 = src[0], q1 = src[1], q2 = src[2], q3 = src[3];
        xT[0][r] = q0; xT[1][r] = q1; xT[2][r] = q2; xT[3][r] = q3;
        f32x2 a_ = pk_mul(f32x2{q0.x, q0.y}, f32x2{q0.x, q0.y});
        a_ = pk_fma(f32x2{q0.z, q0.w}, f32x2{q0.z, q0.w}, a_);
        a_ = pk_fma(f32x2{q1.x, q1.y}, f32x2{q1.x, q1.y}, a_);
        a_ = pk_fma(f32x2{q1.z, q1.w}, f32x2{q1.z, q1.w}, a_);
        a_ = pk_fma(f32x2{q2.x, q2.y}, f32x2{q2.x, q2.y}, a_);
        a_ = pk_fma(f32x2{q2.z, q2.w}, f32x2{q2.z, q2.w}, a_);
        a_ = pk_fma(f32x2{q3.x, q3.y}, f32x2{q3.x, q3.y}, a_);
        a_ = pk_fma(f32x2{q3.z, q3.w}, f32x2{q3.z, q3.w}, a_);
        sqT[r] = a_.x + a_.y;
    }
    if (tid < 64) ((float*)pkt)[tid] = BIGF;

    // y tile: 2 cols/lane; prescale -2; acc seeds {ysq, 0}
    const int j0 = 2 * (64 * W + l);
    f32x2 y0[8], y1[8];
    const float* yp0 = s2 + ((size_t)b * TL + j0) * TD;
    #pragma unroll
    for (int k = 0; k < 8; ++k) {
        y0[k] = *(const f32x2*)(yp0 + 2 * k);
        y1[k] = *(const f32x2*)(yp0 + TD + 2 * k);
    }
    f32x2 s0a = pk_mul(y0[0], y0[0]), s1a = pk_mul(y1[0], y1[0]);
    #pragma unroll
    for (int k = 1; k < 8; ++k) {
        s0a = pk_fma(y0[k], y0[k], s0a);
        s1a = pk_fma(y1[k], y1[k], s1a);
    }
    const f32x2 ys0 = {s0a.x + s0a.y, 0.f};
    const f32x2 ys1 = {s1a.x + s1a.y, 0.f};
    #pragma unroll
    for (int k = 0; k < 8; ++k) {
        y0[k] = pk_mul(y0[k], f32x2{-2.f, -2.f});
        y1[k] = pk_mul(y1[k], f32x2{-2.f, -2.f});
    }

    __syncthreads();

    const unsigned xb = (unsigned)(uintptr_t)&xT[0][0];
    const unsigned sb = (unsigned)(uintptr_t)&sqT[0];
    const int gL = WOFF * W + l;
    const bool lane0 = (l == 0);
    float pv0 = INFF, pv1 = INFF, o1 = INFF;
    float carry = (W == 0) ? 0.f : BIGF;   // lane0 diag seed DTW[-1][-1]=0

    XR x0, x1, x2, x3;
    xissue(xb, sb, 0 - gL, x0);
    xissue(xb, sb, 1 - gL, x1);
    xissue(xb, sb, 2 - gL, x2);

    for (int e = 0; e < NE; ++e) {
        float lb0 = BIGF, lb1 = BIGF, lb2 = BIGF, lb3 = BIGF;
        float lb4 = BIGF, lb5 = BIGF, lb6 = BIGF, lb7 = BIGF;
        if (W > 0) {
            f32x4 pA = pkt[(e + 1) & 1][W - 1][0];
            f32x4 pB = pkt[(e + 1) & 1][W - 1][1];
            lb0 = pA.x; lb1 = pA.y; lb2 = pA.z; lb3 = pA.w;
            lb4 = pB.x; lb5 = pB.y; lb6 = pB.z; lb7 = pB.w;
        }
        const int rb = EP * e - gL;
        float t0, t1, t2, t3, t4, t5, t6, t7;

        WAITC(); xissue(xb, sb, rb + 3,  x3);
        sub(x0, rb + 0, y0, y1, ys0, ys1, pv0, pv1, o1, lb0, carry, lane0); t0 = pv1;
        WAITC(); xissue(xb, sb, rb + 4,  x0);
        sub(x1, rb + 1, y0, y1, ys0, ys1, pv0, pv1, o1, lb1, lb0, lane0);   t1 = pv1;
        WAITC(); xissue(xb, sb, rb + 5,  x1);
        sub(x2, rb + 2, y0, y1, ys0, ys1, pv0, pv1, o1, lb2, lb1, lane0);   t2 = pv1;
        WAITC(); xissue(xb, sb, rb + 6,  x2);
        sub(x3, rb + 3, y0, y1, ys0, ys1, pv0, pv1, o1, lb3, lb2, lane0);   t3 = pv1;
        WAITC(); xissue(xb, sb, rb + 7,  x3);
        sub(x0, rb + 4, y0, y1, ys0, ys1, pv0, pv1, o1, lb4, lb3, lane0);   t4 = pv1;
        WAITC(); xissue(xb, sb, rb + 8,  x0);
        sub(x1, rb + 5, y0, y1, ys0, ys1, pv0, pv1, o1, lb5, lb4, lane0);   t5 = pv1;
        WAITC(); xissue(xb, sb, rb + 9,  x1);
        sub(x2, rb + 6, y0, y1, ys0, ys1, pv0, pv1, o1, lb6, lb5, lane0);   t6 = pv1;
        WAITC(); xissue(xb, sb, rb + 10, x2);
        sub(x3, rb + 7, y0, y1, ys0, ys1, pv0, pv1, o1, lb7, lb6, lane0);   t7 = pv1;

        carry = lb7;

        if (l == 63 && W < 3) {
            pkt[e & 1][W][0] = f32x4{t0, t1, t2, t3};
            pkt[e & 1][W][1] = f32x4{t4, t5, t6, t7};
        }
        __syncthreads();
    }

    if (W == 3 && l == 63) ws[b] = sqrtf(pv1);   // DTW[511][511]
}

__global__ void dtw_reduce_kernel(const float* __restrict__ ws, float* __restrict__ out) {
    const int t = threadIdx.x;          // 64 threads
    float v = ws[t] + ws[t + 64];
    #pragma unroll
    for (int d2 = 32; d2 > 0; d2 >>= 1) v += __shfl_down(v, d2);
    if (t == 0) out[0] = v * (1.0f / TNB);
}

extern "C" void kernel_launch(void* const* d_in, const int* in_sizes, int n_in,
                              void* d_out, int out_size, void* d_ws, size_t ws_size,
                              hipStream_t stream) {
    const float* s1 = (const float*)d_in[0];
    const float* s2 = (const float*)d_in[1];
    float* ws  = (float*)d_ws;
    float* out = (float*)d_out;

    dtw_split_kernel<<<TNB, 256, 0, stream>>>(s1, s2, ws);
    dtw_reduce_kernel<<<1, 64, 0, stream>>>(ws, out);
}